// Round 1
// baseline (4690.314 us; speedup 1.0000x reference)
//
#include <hip/hip_runtime.h>
#include <hip/hip_bf16.h>

// ---------------- problem constants ----------------
#define BATCH 32
#define NPATCH 196
#define PD 768      // patch dim
#define DH 3072     // hidden
#define FD 512      // feat dim
#define MH 128      // metanet hidden
#define NT 8        // num task vectors

// ---------------- generic tiled SGEMM --------------
// C[z] = act( A[z] @ (B[z] + sum_t coefs[z,t]*dB[t]) + (bias + sum_t coefs[z,t]*dbias[t]) )
#define BM 64
#define BN 64
#define BK 16
#define TM 4
#define TN 4

__global__ __launch_bounds__(256)
void gemm_fused(const float* __restrict__ A, const float* __restrict__ B,
                const float* __restrict__ dB,      // [NT,K,N] or null
                const float* __restrict__ bias,    // [N] or null
                const float* __restrict__ dbias,   // [NT,N] or null
                const float* __restrict__ coefs,   // [batch,NT] or null
                float* __restrict__ C,
                int M, int N, int K,
                long sA, long sB, long sC,         // per-z element strides
                int relu)
{
    const int z = blockIdx.z;
    A += (long)z * sA;
    B += (long)z * sB;
    C += (long)z * sC;

    __shared__ float As[BK][BM + 4];
    __shared__ float Bs[BK][BN + 4];

    const int tid = threadIdx.x;
    const int tx = tid & 15;     // 0..15 -> col group
    const int ty = tid >> 4;     // 0..15 -> row group
    const int m0 = blockIdx.y * BM;
    const int n0 = blockIdx.x * BN;

    float c8[NT];
    if (coefs) {
#pragma unroll
        for (int t = 0; t < NT; ++t) c8[t] = coefs[z * NT + t];
    }

    float acc[TM][TN] = {};

    for (int k0 = 0; k0 < K; k0 += BK) {
        // ---- stage A tile (rows m0..m0+63, cols k0..k0+15) transposed into As[k][m]
#pragma unroll
        for (int r = 0; r < 4; ++r) {
            int lin = tid + r * 256;       // 0..1023
            int mm = lin >> 4;             // 0..63
            int kk = lin & 15;             // 0..15
            int gm = m0 + mm;
            float v = 0.f;
            if (gm < M) v = A[(long)gm * K + (k0 + kk)];
            As[kk][mm] = v;
        }
        // ---- stage B tile (rows k0..k0+15, cols n0..n0+63) with fused delta
#pragma unroll
        for (int r = 0; r < 4; ++r) {
            int lin = tid + r * 256;       // 0..1023
            int kk = lin >> 6;             // 0..15
            int nn = lin & 63;             // 0..63
            int gn = n0 + nn;
            float v = 0.f;
            if (gn < N) {
                long off = (long)(k0 + kk) * N + gn;
                v = B[off];
                if (dB) {
                    long tkn = (long)K * N;
#pragma unroll
                    for (int t = 0; t < NT; ++t)
                        v = fmaf(c8[t], dB[(long)t * tkn + off], v);
                }
            }
            Bs[kk][nn] = v;
        }
        __syncthreads();

#pragma unroll
        for (int kk = 0; kk < BK; ++kk) {
            float a[TM], b[TN];
#pragma unroll
            for (int i = 0; i < TM; ++i) a[i] = As[kk][ty * TM + i];
#pragma unroll
            for (int j = 0; j < TN; ++j) b[j] = Bs[kk][tx * TN + j];
#pragma unroll
            for (int i = 0; i < TM; ++i)
#pragma unroll
                for (int j = 0; j < TN; ++j)
                    acc[i][j] = fmaf(a[i], b[j], acc[i][j]);
        }
        __syncthreads();
    }

    // ---- epilogue: bias (+delta bias), relu, store
    float be[TN] = {0.f, 0.f, 0.f, 0.f};
#pragma unroll
    for (int j = 0; j < TN; ++j) {
        int gn = n0 + tx * TN + j;
        if (gn < N) {
            float v = bias ? bias[gn] : 0.f;
            if (dbias) {
#pragma unroll
                for (int t = 0; t < NT; ++t)
                    v = fmaf(c8[t], dbias[(long)t * N + gn], v);
            }
            be[j] = v;
        }
    }
#pragma unroll
    for (int i = 0; i < TM; ++i) {
        int gm = m0 + ty * TM + i;
        if (gm >= M) continue;
#pragma unroll
        for (int j = 0; j < TN; ++j) {
            int gn = n0 + tx * TN + j;
            if (gn >= N) continue;
            float v = acc[i][j] + be[j];
            if (relu) v = fmaxf(v, 0.f);
            C[(long)gm * N + gn] = v;
        }
    }
}

// ---------------- patchify ----------------
// p[b, pr*14+pc, c*256+r*16+s] = x[b, c, pr*16+r, pc*16+s]
__global__ void patchify_kernel(const float* __restrict__ x, float* __restrict__ p, int total)
{
    int i = blockIdx.x * blockDim.x + threadIdx.x;
    if (i >= total) return;
    int d = i % PD;
    int rest = i / PD;
    int patch = rest % NPATCH;
    int b = rest / NPATCH;
    int c = d >> 8;            // /256
    int r = (d >> 4) & 15;
    int s = d & 15;
    int pr = patch / 14;
    int pc = patch % 14;
    p[i] = x[((long)(b * 3 + c) * 224 + (pr * 16 + r)) * 224 + (pc * 16 + s)];
}

// ---------------- mean pool over patches ----------------
__global__ void meanpool_kernel(const float* __restrict__ h2, float* __restrict__ out, int total, int F)
{
    int i = blockIdx.x * blockDim.x + threadIdx.x;   // over BATCH*F
    if (i >= total) return;
    int f = i % F;
    int b = i / F;
    const float* src = h2 + (long)b * NPATCH * F + f;
    float s = 0.f;
    for (int p = 0; p < NPATCH; ++p) s += src[(long)p * F];
    out[i] = s * (1.0f / NPATCH);
}

// ---------------- metanet layer-2 (tiny) ----------------
__global__ void coef_kernel(const float* __restrict__ hidden, const float* __restrict__ mW2,
                            const float* __restrict__ mb2, float* __restrict__ coefs)
{
    int i = threadIdx.x;            // 256 = 32*8
    int t = i & 7;
    int b = i >> 3;
    float s = mb2[t];
    for (int k = 0; k < MH; ++k)
        s = fmaf(hidden[b * MH + k], mW2[k * NT + t], s);
    coefs[i] = s;
}

// ---------------- final combine ----------------
// out[b,f] = main[b,f] + sum_t coefs[b,t]*(v[t,b,f] + db3[t,f])
__global__ void final_kernel(const float* __restrict__ mainbf, const float* __restrict__ v,
                             const float* __restrict__ coefs, const float* __restrict__ db3,
                             float* __restrict__ out)
{
    int i = blockIdx.x * blockDim.x + threadIdx.x;  // 32*512
    if (i >= BATCH * FD) return;
    int f = i % FD;
    int b = i / FD;
    float s = mainbf[i];
#pragma unroll
    for (int t = 0; t < NT; ++t)
        s = fmaf(coefs[b * NT + t], v[((long)t * BATCH + b) * FD + f] + db3[t * FD + f], s);
    out[i] = s;
}

// ---------------- launcher ----------------
extern "C" void kernel_launch(void* const* d_in, const int* in_sizes, int n_in,
                              void* d_out, int out_size, void* d_ws, size_t ws_size,
                              hipStream_t stream)
{
    const float* x   = (const float*)d_in[0];
    const float* W1  = (const float*)d_in[1];
    const float* b1  = (const float*)d_in[2];
    const float* W2  = (const float*)d_in[3];
    const float* b2  = (const float*)d_in[4];
    const float* W3  = (const float*)d_in[5];
    const float* b3  = (const float*)d_in[6];
    const float* dW1 = (const float*)d_in[7];
    const float* db1 = (const float*)d_in[8];
    const float* dW2 = (const float*)d_in[9];
    const float* db2 = (const float*)d_in[10];
    const float* dW3 = (const float*)d_in[11];
    const float* db3 = (const float*)d_in[12];
    const float* mW1 = (const float*)d_in[13];
    const float* mb1 = (const float*)d_in[14];
    const float* mW2 = (const float*)d_in[15];
    const float* mb2 = (const float*)d_in[16];
    float* out = (float*)d_out;

    // workspace carve-up (floats)
    float* ws = (float*)d_ws;
    size_t off = 0;
    float* p    = ws + off; off += (size_t)BATCH * NPATCH * PD;   // 4,816,896
    float* h    = ws + off; off += (size_t)BATCH * NPATCH * PD;   // 4,816,896
    float* h2   = ws + off; off += (size_t)BATCH * NPATCH * DH;   // 19,267,584
    float* h2m  = ws + off; off += (size_t)BATCH * DH;            // 98,304
    float* h2m2 = ws + off; off += (size_t)BATCH * DH;            // 98,304
    float* base = ws + off; off += (size_t)BATCH * FD;
    float* hid  = ws + off; off += (size_t)BATCH * MH;
    float* cf   = ws + off; off += (size_t)BATCH * NT;
    float* vbuf = ws + off; off += (size_t)NT * BATCH * FD;       // 131,072
    float* mainb= ws + off; off += (size_t)BATCH * FD;
    (void)ws_size; (void)n_in; (void)in_sizes; (void)out_size;

    const int M1 = BATCH * NPATCH;   // 6272

    // 1. patchify
    {
        int total = BATCH * NPATCH * PD;
        patchify_kernel<<<(total + 255) / 256, 256, 0, stream>>>(x, p, total);
    }
    // 2. h = relu(p @ W1 + b1)   [6272,768]
    gemm_fused<<<dim3(PD / BN, M1 / BM, 1), 256, 0, stream>>>(
        p, W1, nullptr, b1, nullptr, nullptr, h, M1, PD, PD, 0, 0, 0, 1);
    // 3. h2 = relu(h @ W2 + b2)  [6272,3072]
    gemm_fused<<<dim3(DH / BN, M1 / BM, 1), 256, 0, stream>>>(
        h, W2, nullptr, b2, nullptr, nullptr, h2, M1, DH, PD, 0, 0, 0, 1);
    // 4. mean pool -> h2m [32,3072]
    {
        int total = BATCH * DH;
        meanpool_kernel<<<(total + 255) / 256, 256, 0, stream>>>(h2, h2m, total, DH);
    }
    // 5. base = h2m @ W3 + b3   [32,512]
    gemm_fused<<<dim3(FD / BN, 1, 1), 256, 0, stream>>>(
        h2m, W3, nullptr, b3, nullptr, nullptr, base, BATCH, FD, DH, 0, 0, 0, 0);
    // 6. hid = relu(base @ mW1 + mb1)  [32,128]
    gemm_fused<<<dim3(MH / BN, 1, 1), 256, 0, stream>>>(
        base, mW1, nullptr, mb1, nullptr, nullptr, hid, BATCH, MH, FD, 0, 0, 0, 1);
    // 7. coefs = hid @ mW2 + mb2  [32,8]
    coef_kernel<<<1, 256, 0, stream>>>(hid, mW2, mb2, cf);
    // 8. h = relu(p[b] @ (W1 + sum c dW1) + (b1 + sum c db1))   batch=32, M=196
    gemm_fused<<<dim3(PD / BN, (NPATCH + BM - 1) / BM, BATCH), 256, 0, stream>>>(
        p, W1, dW1, b1, db1, cf, h,
        NPATCH, PD, PD, (long)NPATCH * PD, 0, (long)NPATCH * PD, 1);
    // 9. h2 = relu(h[b] @ (W2 + sum c dW2) + (b2 + sum c db2))
    gemm_fused<<<dim3(DH / BN, (NPATCH + BM - 1) / BM, BATCH), 256, 0, stream>>>(
        h, W2, dW2, b2, db2, cf, h2,
        NPATCH, DH, PD, (long)NPATCH * PD, 0, (long)NPATCH * DH, 1);
    // 10. mean pool -> h2m2
    {
        int total = BATCH * DH;
        meanpool_kernel<<<(total + 255) / 256, 256, 0, stream>>>(h2, h2m2, total, DH);
    }
    // 11. main = h2m2 @ W3 + b3
    gemm_fused<<<dim3(FD / BN, 1, 1), 256, 0, stream>>>(
        h2m2, W3, nullptr, b3, nullptr, nullptr, mainb, BATCH, FD, DH, 0, 0, 0, 0);
    // 12. v[t] = h2m2 @ dW3[t]   batch over t (A shared: sA=0)
    gemm_fused<<<dim3(FD / BN, 1, NT), 256, 0, stream>>>(
        h2m2, dW3, nullptr, nullptr, nullptr, nullptr, vbuf,
        BATCH, FD, DH, 0, (long)DH * FD, (long)BATCH * FD, 0);
    // 13. out = main + sum_t c[b,t]*(v[t,b,:] + db3[t,:])
    {
        int total = BATCH * FD;
        final_kernel<<<(total + 255) / 256, 256, 0, stream>>>(mainb, vbuf, cf, db3, out);
    }
}

// Round 2
// 1685.039 us; speedup vs baseline: 2.7835x; 2.7835x over previous
//
#include <hip/hip_runtime.h>
#include <hip/hip_bf16.h>

// ---------------- problem constants ----------------
#define BATCH 32
#define NPATCH 196
#define PD 768      // patch dim
#define DH 3072     // hidden
#define FD 512      // feat dim
#define MH 128      // metanet hidden
#define NT 8        // num task vectors

typedef unsigned short u16;
typedef u16   u16x8  __attribute__((ext_vector_type(8)));   // 16B vector load
typedef short bf16x8 __attribute__((ext_vector_type(8)));   // MFMA A/B frag (8 bf16)
typedef float f32x4  __attribute__((ext_vector_type(4)));   // MFMA C/D frag

// =====================================================================
// bf16 MFMA batched GEMM:  C[z] = act(A[z] @ BT[z]^T + bias[z])
//   A  : [M,K] bf16 row-major (per-z stride sA elements)
//   BT : [N,K] bf16 row-major (B pre-transposed; per-z stride sB)
//   C  : [M,N] bf16 row-major (per-z stride sC)
//   bias fp32 [N] (per-z stride sBias), optional relu
// Tile: 128x128, BK=32, 256 threads = 4 waves, each wave 64x64 via
// 4x4 grid of mfma_f32_16x16x32_bf16.  N, K must be multiples of 128/32.
// =====================================================================
#define GBM 128
#define GBN 128
#define GBK 32
#define LDK 40   // padded LDS k-stride (bf16 units); 80B rows, 16B-aligned

__global__ __launch_bounds__(256)
void gemm_bf16(const u16* __restrict__ A, const u16* __restrict__ BT,
               const float* __restrict__ bias, u16* __restrict__ C,
               int M, int N, int K,
               long sA, long sB, long sC, long sBias, int relu)
{
    const int z = blockIdx.z;
    A  += (long)z * sA;
    BT += (long)z * sB;
    C  += (long)z * sC;
    const float* bz = bias ? bias + (long)z * sBias : nullptr;

    __shared__ __align__(16) u16 As[GBM * LDK];
    __shared__ __align__(16) u16 Bs[GBN * LDK];

    const int tid  = threadIdx.x;
    const int lane = tid & 63;
    const int wave = tid >> 6;
    const int wr = (wave >> 1) * 64;   // wave row block
    const int wc = (wave & 1) * 64;    // wave col block

    const int m0 = blockIdx.y * GBM;
    const int n0 = blockIdx.x * GBN;

    f32x4 acc[4][4] = {};

    const int lrow = lane & 15;
    const int koff = (lane >> 4) * 8;

    for (int k0 = 0; k0 < K; k0 += GBK) {
        // ---- stage A: 128 rows x 32 k, 512 16B-chunks, 2 per thread
#pragma unroll
        for (int r = 0; r < 2; ++r) {
            int ci  = tid + r * 256;
            int row = ci >> 2;
            int c8  = ci & 3;
            int gm  = m0 + row; if (gm >= M) gm = M - 1;   // clamp (stores masked)
            u16x8 v = *(const u16x8*)(A + (long)gm * K + k0 + c8 * 8);
            *(u16x8*)(&As[row * LDK + c8 * 8]) = v;
        }
        // ---- stage B (already [N,K]): identical pattern
#pragma unroll
        for (int r = 0; r < 2; ++r) {
            int ci  = tid + r * 256;
            int row = ci >> 2;
            int c8  = ci & 3;
            u16x8 v = *(const u16x8*)(BT + (long)(n0 + row) * K + k0 + c8 * 8);
            *(u16x8*)(&Bs[row * LDK + c8 * 8]) = v;
        }
        __syncthreads();

        bf16x8 af[4], bfr[4];
#pragma unroll
        for (int i = 0; i < 4; ++i)
            af[i] = *(const bf16x8*)(&As[(wr + i * 16 + lrow) * LDK + koff]);
#pragma unroll
        for (int j = 0; j < 4; ++j)
            bfr[j] = *(const bf16x8*)(&Bs[(wc + j * 16 + lrow) * LDK + koff]);
#pragma unroll
        for (int i = 0; i < 4; ++i)
#pragma unroll
            for (int j = 0; j < 4; ++j)
                acc[i][j] = __builtin_amdgcn_mfma_f32_16x16x32_bf16(af[i], bfr[j], acc[i][j], 0, 0, 0);
        __syncthreads();
    }

    // ---- epilogue: C/D layout col=lane&15, row=(lane>>4)*4+reg
    const int crow = (lane >> 4) * 4;
    const int ccol = lane & 15;
#pragma unroll
    for (int j = 0; j < 4; ++j) {
        int gn = n0 + wc + j * 16 + ccol;
        float bv = bz ? bz[gn] : 0.f;
#pragma unroll
        for (int i = 0; i < 4; ++i) {
#pragma unroll
            for (int rg = 0; rg < 4; ++rg) {
                int gm = m0 + wr + i * 16 + crow + rg;
                if (gm < M) {
                    float v = acc[i][j][rg] + bv;
                    if (relu) v = fmaxf(v, 0.f);
                    __hip_bfloat16 hv = __float2bfloat16(v);
                    C[(long)gm * N + gn] = *(u16*)&hv;
                }
            }
        }
    }
}

// =====================================================================
// fp32 tiled GEMM (small layer-3 / metanet shapes) — proven in round 0
// =====================================================================
#define BM 64
#define BN 64
#define BK 16
#define TM 4
#define TN 4

__global__ __launch_bounds__(256)
void gemm_fused(const float* __restrict__ A, const float* __restrict__ B,
                const float* __restrict__ bias,
                float* __restrict__ C,
                int M, int N, int K,
                long sA, long sB, long sC, int relu)
{
    const int z = blockIdx.z;
    A += (long)z * sA;
    B += (long)z * sB;
    C += (long)z * sC;

    __shared__ float As2[BK][BM + 4];
    __shared__ float Bs2[BK][BN + 4];

    const int tid = threadIdx.x;
    const int tx = tid & 15;
    const int ty = tid >> 4;
    const int m0 = blockIdx.y * BM;
    const int n0 = blockIdx.x * BN;

    float acc[TM][TN] = {};

    for (int k0 = 0; k0 < K; k0 += BK) {
#pragma unroll
        for (int r = 0; r < 4; ++r) {
            int lin = tid + r * 256;
            int mm = lin >> 4;
            int kk = lin & 15;
            int gm = m0 + mm;
            As2[kk][mm] = (gm < M) ? A[(long)gm * K + (k0 + kk)] : 0.f;
        }
#pragma unroll
        for (int r = 0; r < 4; ++r) {
            int lin = tid + r * 256;
            int kk = lin >> 6;
            int nn = lin & 63;
            int gn = n0 + nn;
            Bs2[kk][nn] = (gn < N) ? B[(long)(k0 + kk) * N + gn] : 0.f;
        }
        __syncthreads();
#pragma unroll
        for (int kk = 0; kk < BK; ++kk) {
            float a[TM], b[TN];
#pragma unroll
            for (int i = 0; i < TM; ++i) a[i] = As2[kk][ty * TM + i];
#pragma unroll
            for (int j = 0; j < TN; ++j) b[j] = Bs2[kk][tx * TN + j];
#pragma unroll
            for (int i = 0; i < TM; ++i)
#pragma unroll
                for (int j = 0; j < TN; ++j)
                    acc[i][j] = fmaf(a[i], b[j], acc[i][j]);
        }
        __syncthreads();
    }
#pragma unroll
    for (int i = 0; i < TM; ++i) {
        int gm = m0 + ty * TM + i;
        if (gm >= M) continue;
#pragma unroll
        for (int j = 0; j < TN; ++j) {
            int gn = n0 + tx * TN + j;
            if (gn >= N) continue;
            float v = acc[i][j] + (bias ? bias[gn] : 0.f);
            if (relu) v = fmaxf(v, 0.f);
            C[(long)gm * N + gn] = v;
        }
    }
}

// ---------------- patchify -> bf16 ----------------
__global__ void patchify_bf(const float* __restrict__ x, u16* __restrict__ p, int total)
{
    int i = blockIdx.x * blockDim.x + threadIdx.x;
    if (i >= total) return;
    int d = i % PD;
    int rest = i / PD;
    int patch = rest % NPATCH;
    int b = rest / NPATCH;
    int c = d >> 8;
    int r = (d >> 4) & 15;
    int s = d & 15;
    int pr = patch / 14;
    int pc = patch % 14;
    float v = x[((long)(b * 3 + c) * 224 + (pr * 16 + r)) * 224 + (pc * 16 + s)];
    __hip_bfloat16 hv = __float2bfloat16(v);
    p[i] = *(u16*)&hv;
}

// ---------------- W [K,N] fp32 -> WT [N,K] bf16 (LDS tile transpose) ----
__global__ __launch_bounds__(256)
void wtrans(const float* __restrict__ W, u16* __restrict__ out, int K, int N)
{
    __shared__ float Ws[32][33];
    const int tid = threadIdx.x;
    const int k0 = blockIdx.x * 32;
    const int n0 = blockIdx.y * 32;
#pragma unroll
    for (int r = 0; r < 4; ++r) {
        int idx = tid + r * 256;
        int kk = idx >> 5, nn = idx & 31;
        Ws[kk][nn] = W[(long)(k0 + kk) * N + n0 + nn];
    }
    __syncthreads();
#pragma unroll
    for (int r = 0; r < 4; ++r) {
        int idx = tid + r * 256;
        int kk = idx & 31, nn = idx >> 5;
        __hip_bfloat16 hv = __float2bfloat16(Ws[kk][nn]);
        out[(long)(n0 + nn) * K + k0 + kk] = *(u16*)&hv;
    }
}

// ---------------- composed weights: out[b][n][k] = W[k][n] + sum_t cf[b,t] dW[t][k][n]
__global__ __launch_bounds__(256)
void compose_w(const float* __restrict__ W, const float* __restrict__ dW,
               const float* __restrict__ cf, u16* __restrict__ out,
               int K, int N)
{
    __shared__ float Ws[9][32][33];
    const int tid = threadIdx.x;
    const int k0 = blockIdx.x * 32;
    const int n0 = blockIdx.y * 32;
    const long tKN = (long)K * N;
#pragma unroll
    for (int r = 0; r < 4; ++r) {
        int idx = tid + r * 256;
        int kk = idx >> 5, nn = idx & 31;
        Ws[0][kk][nn] = W[(long)(k0 + kk) * N + n0 + nn];
    }
    for (int t = 0; t < NT; ++t) {
#pragma unroll
        for (int r = 0; r < 4; ++r) {
            int idx = tid + r * 256;
            int kk = idx >> 5, nn = idx & 31;
            Ws[t + 1][kk][nn] = dW[t * tKN + (long)(k0 + kk) * N + n0 + nn];
        }
    }
    __syncthreads();
    for (int b = 0; b < BATCH; ++b) {
        float cc[NT];
#pragma unroll
        for (int t = 0; t < NT; ++t) cc[t] = cf[b * NT + t];
#pragma unroll
        for (int r = 0; r < 4; ++r) {
            int idx = tid + r * 256;
            int kk = idx & 31, nn = idx >> 5;   // k fastest -> coalesced writes
            float v = Ws[0][kk][nn];
#pragma unroll
            for (int t = 0; t < NT; ++t) v = fmaf(cc[t], Ws[t + 1][kk][nn], v);
            __hip_bfloat16 hv = __float2bfloat16(v);
            out[((long)b * N + (n0 + nn)) * K + k0 + kk] = *(u16*)&hv;
        }
    }
}

// ---------------- composed bias: out[b][n] = bsrc[n] + sum_t cf[b,t] db[t][n]
__global__ void compose_bias(const float* __restrict__ bsrc, const float* __restrict__ db,
                             const float* __restrict__ cf, float* __restrict__ out, int N)
{
    int i = blockIdx.x * blockDim.x + threadIdx.x;
    if (i >= BATCH * N) return;
    int n = i % N, b = i / N;
    float v = bsrc[n];
#pragma unroll
    for (int t = 0; t < NT; ++t) v = fmaf(cf[b * NT + t], db[(long)t * N + n], v);
    out[i] = v;
}

// ---------------- mean pool over patches (bf16 in, fp32 out) ----------
__global__ void meanpool_bf(const u16* __restrict__ h2, float* __restrict__ out, int total, int F)
{
    int i = blockIdx.x * blockDim.x + threadIdx.x;
    if (i >= total) return;
    int f = i % F;
    int b = i / F;
    const u16* src = h2 + (long)b * NPATCH * F + f;
    float s = 0.f;
    for (int p = 0; p < NPATCH; ++p) {
        u16 raw = src[(long)p * F];
        __hip_bfloat16 hv = *(__hip_bfloat16*)&raw;
        s += __bfloat162float(hv);
    }
    out[i] = s * (1.0f / NPATCH);
}

// ---------------- metanet layer-2 (tiny) ----------------
__global__ void coef_kernel(const float* __restrict__ hidden, const float* __restrict__ mW2,
                            const float* __restrict__ mb2, float* __restrict__ coefs)
{
    int i = threadIdx.x;            // 256 = 32*8
    int t = i & 7;
    int b = i >> 3;
    float s = mb2[t];
    for (int k = 0; k < MH; ++k)
        s = fmaf(hidden[b * MH + k], mW2[k * NT + t], s);
    coefs[i] = s;
}

// ---------------- final combine ----------------
__global__ void final_kernel(const float* __restrict__ mainbf, const float* __restrict__ v,
                             const float* __restrict__ coefs, const float* __restrict__ db3,
                             float* __restrict__ out)
{
    int i = blockIdx.x * blockDim.x + threadIdx.x;
    if (i >= BATCH * FD) return;
    int f = i % FD;
    int b = i / FD;
    float s = mainbf[i];
#pragma unroll
    for (int t = 0; t < NT; ++t)
        s = fmaf(coefs[b * NT + t], v[((long)t * BATCH + b) * FD + f] + db3[t * FD + f], s);
    out[i] = s;
}

// ---------------- launcher ----------------
extern "C" void kernel_launch(void* const* d_in, const int* in_sizes, int n_in,
                              void* d_out, int out_size, void* d_ws, size_t ws_size,
                              hipStream_t stream)
{
    const float* x   = (const float*)d_in[0];
    const float* W1  = (const float*)d_in[1];
    const float* b1  = (const float*)d_in[2];
    const float* W2  = (const float*)d_in[3];
    const float* b2  = (const float*)d_in[4];
    const float* W3  = (const float*)d_in[5];
    const float* b3  = (const float*)d_in[6];
    const float* dW1 = (const float*)d_in[7];
    const float* db1 = (const float*)d_in[8];
    const float* dW2 = (const float*)d_in[9];
    const float* db2 = (const float*)d_in[10];
    const float* dW3 = (const float*)d_in[11];
    const float* db3 = (const float*)d_in[12];
    const float* mW1 = (const float*)d_in[13];
    const float* mb1 = (const float*)d_in[14];
    const float* mW2 = (const float*)d_in[15];
    const float* mb2 = (const float*)d_in[16];
    float* out = (float*)d_out;
    (void)n_in; (void)in_sizes; (void)out_size; (void)ws_size;

    // workspace carve-up (256B aligned)
    char* w = (char*)d_ws;
    auto carve = [&](size_t bytes) { void* q = (void*)w; w += (bytes + 255) & ~(size_t)255; return q; };
    const int M1 = BATCH * NPATCH;   // 6272

    u16*  p_bf  = (u16*)carve((size_t)M1 * PD * 2);            // 9.6 MB
    u16*  h_bf  = (u16*)carve((size_t)M1 * PD * 2);            // 9.6 MB
    u16*  h2_bf = (u16*)carve((size_t)M1 * DH * 2);            // 38.5 MB
    u16*  W1T   = (u16*)carve((size_t)PD * PD * 2);            // 1.2 MB
    u16*  W2T   = (u16*)carve((size_t)PD * DH * 2);            // 4.7 MB
    u16*  W1bT  = (u16*)carve((size_t)BATCH * PD * PD * 2);    // 37.7 MB
    u16*  W2bT  = (u16*)carve((size_t)BATCH * DH * PD * 2);    // 151 MB
    float* b1b  = (float*)carve((size_t)BATCH * PD * 4);
    float* b2b  = (float*)carve((size_t)BATCH * DH * 4);
    float* h2m  = (float*)carve((size_t)BATCH * DH * 4);
    float* h2m2 = (float*)carve((size_t)BATCH * DH * 4);
    float* base = (float*)carve((size_t)BATCH * FD * 4);
    float* hid  = (float*)carve((size_t)BATCH * MH * 4);
    float* cf   = (float*)carve((size_t)BATCH * NT * 4);
    float* vbuf = (float*)carve((size_t)NT * BATCH * FD * 4);
    float* mainb= (float*)carve((size_t)BATCH * FD * 4);

    // 1. patchify -> bf16
    {
        int total = M1 * PD;
        patchify_bf<<<(total + 255) / 256, 256, 0, stream>>>(x, p_bf, total);
    }
    // 2. transpose shared weights to [N,K] bf16
    wtrans<<<dim3(PD / 32, PD / 32), 256, 0, stream>>>(W1, W1T, PD, PD);
    wtrans<<<dim3(PD / 32, DH / 32), 256, 0, stream>>>(W2, W2T, PD, DH);
    // 3. phase-1 L1: h = relu(p @ W1 + b1)
    gemm_bf16<<<dim3(PD / GBN, M1 / GBM, 1), 256, 0, stream>>>(
        p_bf, W1T, b1, h_bf, M1, PD, PD, 0, 0, 0, 0, 1);
    // 4. phase-1 L2: h2 = relu(h @ W2 + b2)
    gemm_bf16<<<dim3(DH / GBN, M1 / GBM, 1), 256, 0, stream>>>(
        h_bf, W2T, b2, h2_bf, M1, DH, PD, 0, 0, 0, 0, 1);
    // 5. mean pool -> h2m
    {
        int total = BATCH * DH;
        meanpool_bf<<<(total + 255) / 256, 256, 0, stream>>>(h2_bf, h2m, total, DH);
    }
    // 6. base = h2m @ W3 + b3   (fp32)
    gemm_fused<<<dim3(FD / BN, 1, 1), 256, 0, stream>>>(
        h2m, W3, b3, base, BATCH, FD, DH, 0, 0, 0, 0);
    // 7. hid = relu(base @ mW1 + mb1)
    gemm_fused<<<dim3(MH / BN, 1, 1), 256, 0, stream>>>(
        base, mW1, mb1, hid, BATCH, MH, FD, 0, 0, 0, 1);
    // 8. coefs
    coef_kernel<<<1, 256, 0, stream>>>(hid, mW2, mb2, cf);
    // 9. compose per-sample weights (transposed bf16) + biases (fp32)
    compose_w<<<dim3(PD / 32, PD / 32), 256, 0, stream>>>(W1, dW1, cf, W1bT, PD, PD);
    compose_w<<<dim3(PD / 32, DH / 32), 256, 0, stream>>>(W2, dW2, cf, W2bT, PD, DH);
    compose_bias<<<(BATCH * PD + 255) / 256, 256, 0, stream>>>(b1, db1, cf, b1b, PD);
    compose_bias<<<(BATCH * DH + 255) / 256, 256, 0, stream>>>(b2, db2, cf, b2b, DH);
    // 10. phase-2 L1: h = relu(p[b] @ W1b[b] + b1b[b])   z=32, M=196
    gemm_bf16<<<dim3(PD / GBN, 2, BATCH), 256, 0, stream>>>(
        p_bf, W1bT, b1b, h_bf, NPATCH, PD, PD,
        (long)NPATCH * PD, (long)PD * PD, (long)NPATCH * PD, PD, 1);
    // 11. phase-2 L2: h2 = relu(h[b] @ W2b[b] + b2b[b])
    gemm_bf16<<<dim3(DH / GBN, 2, BATCH), 256, 0, stream>>>(
        h_bf, W2bT, b2b, h2_bf, NPATCH, DH, PD,
        (long)NPATCH * PD, (long)DH * PD, (long)NPATCH * DH, DH, 1);
    // 12. mean pool -> h2m2
    {
        int total = BATCH * DH;
        meanpool_bf<<<(total + 255) / 256, 256, 0, stream>>>(h2_bf, h2m2, total, DH);
    }
    // 13. main = h2m2 @ W3 + b3 (fp32)
    gemm_fused<<<dim3(FD / BN, 1, 1), 256, 0, stream>>>(
        h2m2, W3, b3, mainb, BATCH, FD, DH, 0, 0, 0, 0);
    // 14. v[t] = h2m2 @ dW3[t]  (fp32, z=8)
    gemm_fused<<<dim3(FD / BN, 1, NT), 256, 0, stream>>>(
        h2m2, dW3, nullptr, vbuf, BATCH, FD, DH, 0, (long)DH * FD, (long)BATCH * FD, 0);
    // 15. out = main + sum_t c[b,t]*(v[t,b,:] + db3[t,:])
    {
        int total = BATCH * FD;
        final_kernel<<<(total + 255) / 256, 256, 0, stream>>>(mainb, vbuf, cf, db3, out);
    }
}

// Round 3
// 663.236 us; speedup vs baseline: 7.0719x; 2.5406x over previous
//
#include <hip/hip_runtime.h>
#include <hip/hip_bf16.h>

// ---------------- problem constants ----------------
#define BATCH 32
#define NPATCH 196
#define PD 768      // patch dim
#define DH 3072     // hidden
#define FD 512      // feat dim
#define MH 128      // metanet hidden
#define NT 8        // num task vectors

typedef unsigned short u16;
typedef u16   u16x8  __attribute__((ext_vector_type(8)));   // 16B vector load
typedef short bf16x8 __attribute__((ext_vector_type(8)));   // MFMA A/B frag (8 bf16)
typedef float f32x4  __attribute__((ext_vector_type(4)));   // MFMA C/D frag

// =====================================================================
// bf16 MFMA batched GEMM:  C[z] = act(A[z] @ BT[z]^T + bias[z])
// Tile: 128x128, BK=32, 256 threads = 4 waves, each wave 64x64 via
// 4x4 grid of mfma_f32_16x16x32_bf16.  N, K multiples of 128/32.
// =====================================================================
#define GBM 128
#define GBN 128
#define GBK 32
#define LDK 40   // padded LDS k-stride (bf16 units)

__global__ __launch_bounds__(256)
void gemm_bf16(const u16* __restrict__ A, const u16* __restrict__ BT,
               const float* __restrict__ bias, u16* __restrict__ C,
               int M, int N, int K,
               long sA, long sB, long sC, long sBias, int relu)
{
    const int z = blockIdx.z;
    A  += (long)z * sA;
    BT += (long)z * sB;
    C  += (long)z * sC;
    const float* bz = bias ? bias + (long)z * sBias : nullptr;

    __shared__ __align__(16) u16 As[GBM * LDK];
    __shared__ __align__(16) u16 Bs[GBN * LDK];

    const int tid  = threadIdx.x;
    const int lane = tid & 63;
    const int wave = tid >> 6;
    const int wr = (wave >> 1) * 64;
    const int wc = (wave & 1) * 64;

    const int m0 = blockIdx.y * GBM;
    const int n0 = blockIdx.x * GBN;

    f32x4 acc[4][4] = {};

    const int lrow = lane & 15;
    const int koff = (lane >> 4) * 8;

    for (int k0 = 0; k0 < K; k0 += GBK) {
#pragma unroll
        for (int r = 0; r < 2; ++r) {
            int ci  = tid + r * 256;
            int row = ci >> 2;
            int c8  = ci & 3;
            int gm  = m0 + row; if (gm >= M) gm = M - 1;
            u16x8 v = *(const u16x8*)(A + (long)gm * K + k0 + c8 * 8);
            *(u16x8*)(&As[row * LDK + c8 * 8]) = v;
        }
#pragma unroll
        for (int r = 0; r < 2; ++r) {
            int ci  = tid + r * 256;
            int row = ci >> 2;
            int c8  = ci & 3;
            u16x8 v = *(const u16x8*)(BT + (long)(n0 + row) * K + k0 + c8 * 8);
            *(u16x8*)(&Bs[row * LDK + c8 * 8]) = v;
        }
        __syncthreads();

        bf16x8 af[4], bfr[4];
#pragma unroll
        for (int i = 0; i < 4; ++i)
            af[i] = *(const bf16x8*)(&As[(wr + i * 16 + lrow) * LDK + koff]);
#pragma unroll
        for (int j = 0; j < 4; ++j)
            bfr[j] = *(const bf16x8*)(&Bs[(wc + j * 16 + lrow) * LDK + koff]);
#pragma unroll
        for (int i = 0; i < 4; ++i)
#pragma unroll
            for (int j = 0; j < 4; ++j)
                acc[i][j] = __builtin_amdgcn_mfma_f32_16x16x32_bf16(af[i], bfr[j], acc[i][j], 0, 0, 0);
        __syncthreads();
    }

    const int crow = (lane >> 4) * 4;
    const int ccol = lane & 15;
#pragma unroll
    for (int j = 0; j < 4; ++j) {
        int gn = n0 + wc + j * 16 + ccol;
        float bv = bz ? bz[gn] : 0.f;
#pragma unroll
        for (int i = 0; i < 4; ++i) {
#pragma unroll
            for (int rg = 0; rg < 4; ++rg) {
                int gm = m0 + wr + i * 16 + crow + rg;
                if (gm < M) {
                    float v = acc[i][j][rg] + bv;
                    if (relu) v = fmaxf(v, 0.f);
                    __hip_bfloat16 hv = __float2bfloat16(v);
                    C[(long)gm * N + gn] = *(u16*)&hv;
                }
            }
        }
    }
}

// =====================================================================
// skinny layer-3: outp[b,f] += sum_k Aeff[b,k] * Bz[k,f]
//   z==0: Bz=B0 (W3),  Aeff = A
//   z>=1: Bz=dB[z-1],  Aeff = cf[b,z-1] * A
// grid: (FD/64, nz, KS); block 256 = 64 f-cols x 4 b-groups (8 b each).
// outp must be pre-initialized (bias); accumulation via atomicAdd.
// =====================================================================
#define L3CHUNK 128

__global__ __launch_bounds__(256)
void skinny3(const float* __restrict__ A,   // [32, DH]
             const float* __restrict__ B0,  // [DH, FD]
             const float* __restrict__ dB,  // [NT, DH, FD] or null
             const float* __restrict__ cf,  // [32, NT] or null
             float* __restrict__ outp,      // [32, FD] pre-init with bias
             int kchunk)
{
    const int z  = blockIdx.y;
    const int k0 = blockIdx.z * kchunk;
    const float* B = (z == 0) ? B0 : dB + (long)(z - 1) * DH * FD;

    __shared__ float Asl[BATCH][L3CHUNK];

    const int tid = threadIdx.x;
    const int n   = blockIdx.x * 64 + (tid & 63);
    const int bg  = tid >> 6;          // 0..3 -> b = bg*8 .. bg*8+7

    float acc[8] = {};

    for (int kc = 0; kc < kchunk; kc += L3CHUNK) {
        // stage A chunk scaled by coef: 32*128 = 4096 elems, 16/thread
#pragma unroll
        for (int r = 0; r < 16; ++r) {
            int idx = tid + r * 256;
            int b = idx >> 7;          // /128
            int k = idx & 127;
            float s = (z == 0) ? 1.f : cf[b * NT + z - 1];
            Asl[b][k] = s * A[(long)b * DH + k0 + kc + k];
        }
        __syncthreads();
#pragma unroll 4
        for (int k = 0; k < L3CHUNK; ++k) {
            float w = B[(long)(k0 + kc + k) * FD + n];
#pragma unroll
            for (int bb = 0; bb < 8; ++bb)
                acc[bb] = fmaf(Asl[bg * 8 + bb][k], w, acc[bb]);
        }
        __syncthreads();
    }
#pragma unroll
    for (int bb = 0; bb < 8; ++bb)
        atomicAdd(&outp[(long)(bg * 8 + bb) * FD + n], acc[bb]);
}

// ---------------- patchify -> bf16 ----------------
__global__ void patchify_bf(const float* __restrict__ x, u16* __restrict__ p, int total)
{
    int i = blockIdx.x * blockDim.x + threadIdx.x;
    if (i >= total) return;
    int d = i % PD;
    int rest = i / PD;
    int patch = rest % NPATCH;
    int b = rest / NPATCH;
    int c = d >> 8;
    int r = (d >> 4) & 15;
    int s = d & 15;
    int pr = patch / 14;
    int pc = patch % 14;
    float v = x[((long)(b * 3 + c) * 224 + (pr * 16 + r)) * 224 + (pc * 16 + s)];
    __hip_bfloat16 hv = __float2bfloat16(v);
    p[i] = *(u16*)&hv;
}

// ---------------- W [K,N] fp32 -> WT [N,K] bf16 ----------------
__global__ __launch_bounds__(256)
void wtrans(const float* __restrict__ W, u16* __restrict__ out, int K, int N)
{
    __shared__ float Ws[32][33];
    const int tid = threadIdx.x;
    const int k0 = blockIdx.x * 32;
    const int n0 = blockIdx.y * 32;
#pragma unroll
    for (int r = 0; r < 4; ++r) {
        int idx = tid + r * 256;
        int kk = idx >> 5, nn = idx & 31;
        Ws[kk][nn] = W[(long)(k0 + kk) * N + n0 + nn];
    }
    __syncthreads();
#pragma unroll
    for (int r = 0; r < 4; ++r) {
        int idx = tid + r * 256;
        int kk = idx & 31, nn = idx >> 5;
        __hip_bfloat16 hv = __float2bfloat16(Ws[kk][nn]);
        out[(long)(n0 + nn) * K + k0 + kk] = *(u16*)&hv;
    }
}

// ---------------- composed weights (bf16, transposed) ----------------
__global__ __launch_bounds__(256)
void compose_w(const float* __restrict__ W, const float* __restrict__ dW,
               const float* __restrict__ cf, u16* __restrict__ out,
               int K, int N)
{
    __shared__ float Ws[9][32][33];
    const int tid = threadIdx.x;
    const int k0 = blockIdx.x * 32;
    const int n0 = blockIdx.y * 32;
    const long tKN = (long)K * N;
#pragma unroll
    for (int r = 0; r < 4; ++r) {
        int idx = tid + r * 256;
        int kk = idx >> 5, nn = idx & 31;
        Ws[0][kk][nn] = W[(long)(k0 + kk) * N + n0 + nn];
    }
    for (int t = 0; t < NT; ++t) {
#pragma unroll
        for (int r = 0; r < 4; ++r) {
            int idx = tid + r * 256;
            int kk = idx >> 5, nn = idx & 31;
            Ws[t + 1][kk][nn] = dW[t * tKN + (long)(k0 + kk) * N + n0 + nn];
        }
    }
    __syncthreads();
    for (int b = 0; b < BATCH; ++b) {
        float cc[NT];
#pragma unroll
        for (int t = 0; t < NT; ++t) cc[t] = cf[b * NT + t];
#pragma unroll
        for (int r = 0; r < 4; ++r) {
            int idx = tid + r * 256;
            int kk = idx & 31, nn = idx >> 5;   // k fastest -> coalesced writes
            float v = Ws[0][kk][nn];
#pragma unroll
            for (int t = 0; t < NT; ++t) v = fmaf(cc[t], Ws[t + 1][kk][nn], v);
            __hip_bfloat16 hv = __float2bfloat16(v);
            out[((long)b * N + (n0 + nn)) * K + k0 + kk] = *(u16*)&hv;
        }
    }
}

// ---------------- bias init: out[b,n] = bsrc[n] + sum_t cf[b,t] db[t][n]
__global__ void compose_bias(const float* __restrict__ bsrc, const float* __restrict__ db,
                             const float* __restrict__ cf, float* __restrict__ out, int N)
{
    int i = blockIdx.x * blockDim.x + threadIdx.x;
    if (i >= BATCH * N) return;
    int n = i % N, b = i / N;
    float v = bsrc[n];
    if (db) {
#pragma unroll
        for (int t = 0; t < NT; ++t) v = fmaf(cf[b * NT + t], db[(long)t * N + n], v);
    }
    out[i] = v;
}

// ---------------- mean pool over patches (bf16 in, fp32 out) ----------
__global__ void meanpool_bf(const u16* __restrict__ h2, float* __restrict__ out, int total, int F)
{
    int i = blockIdx.x * blockDim.x + threadIdx.x;
    if (i >= total) return;
    int f = i % F;
    int b = i / F;
    const u16* src = h2 + (long)b * NPATCH * F + f;
    float s = 0.f;
    for (int p = 0; p < NPATCH; ++p) {
        u16 raw = src[(long)p * F];
        __hip_bfloat16 hv = *(__hip_bfloat16*)&raw;
        s += __bfloat162float(hv);
    }
    out[i] = s * (1.0f / NPATCH);
}

// ---------------- metanet L1: hid = relu(base @ mW1 + mb1), wave/output
__global__ __launch_bounds__(256)
void hid_kernel(const float* __restrict__ base, const float* __restrict__ mW1,
                const float* __restrict__ mb1, float* __restrict__ hid)
{
    int gw   = blockIdx.x * 4 + (threadIdx.x >> 6);   // 0..4095
    int lane = threadIdx.x & 63;
    int b = gw >> 7;          // /128
    int n = gw & 127;
    float s = 0.f;
#pragma unroll
    for (int i = 0; i < FD / 64; ++i) {
        int k = i * 64 + lane;
        s = fmaf(base[b * FD + k], mW1[k * MH + n], s);
    }
#pragma unroll
    for (int off = 32; off; off >>= 1) s += __shfl_down(s, off, 64);
    if (lane == 0) hid[gw] = fmaxf(s + mb1[n], 0.f);
}

// ---------------- metanet L2 (tiny) ----------------
__global__ void coef_kernel(const float* __restrict__ hidden, const float* __restrict__ mW2,
                            const float* __restrict__ mb2, float* __restrict__ coefs)
{
    int i = threadIdx.x;            // 256 = 32*8
    int t = i & 7;
    int b = i >> 3;
    float s = mb2[t];
    for (int k = 0; k < MH; ++k)
        s = fmaf(hidden[b * MH + k], mW2[k * NT + t], s);
    coefs[i] = s;
}

// ---------------- launcher ----------------
extern "C" void kernel_launch(void* const* d_in, const int* in_sizes, int n_in,
                              void* d_out, int out_size, void* d_ws, size_t ws_size,
                              hipStream_t stream)
{
    const float* x   = (const float*)d_in[0];
    const float* W1  = (const float*)d_in[1];
    const float* b1  = (const float*)d_in[2];
    const float* W2  = (const float*)d_in[3];
    const float* b2  = (const float*)d_in[4];
    const float* W3  = (const float*)d_in[5];
    const float* b3  = (const float*)d_in[6];
    const float* dW1 = (const float*)d_in[7];
    const float* db1 = (const float*)d_in[8];
    const float* dW2 = (const float*)d_in[9];
    const float* db2 = (const float*)d_in[10];
    const float* dW3 = (const float*)d_in[11];
    const float* db3 = (const float*)d_in[12];
    const float* mW1 = (const float*)d_in[13];
    const float* mb1 = (const float*)d_in[14];
    const float* mW2 = (const float*)d_in[15];
    const float* mb2 = (const float*)d_in[16];
    float* out = (float*)d_out;
    (void)n_in; (void)in_sizes; (void)out_size; (void)ws_size;

    char* w = (char*)d_ws;
    auto carve = [&](size_t bytes) { void* q = (void*)w; w += (bytes + 255) & ~(size_t)255; return q; };
    const int M1 = BATCH * NPATCH;   // 6272

    u16*  p_bf  = (u16*)carve((size_t)M1 * PD * 2);
    u16*  h_bf  = (u16*)carve((size_t)M1 * PD * 2);
    u16*  h2_bf = (u16*)carve((size_t)M1 * DH * 2);
    u16*  W1T   = (u16*)carve((size_t)PD * PD * 2);
    u16*  W2T   = (u16*)carve((size_t)PD * DH * 2);
    u16*  W1bT  = (u16*)carve((size_t)BATCH * PD * PD * 2);
    u16*  W2bT  = (u16*)carve((size_t)BATCH * DH * PD * 2);
    float* b1b  = (float*)carve((size_t)BATCH * PD * 4);
    float* b2b  = (float*)carve((size_t)BATCH * DH * 4);
    float* h2m  = (float*)carve((size_t)BATCH * DH * 4);
    float* h2m2 = (float*)carve((size_t)BATCH * DH * 4);
    float* base = (float*)carve((size_t)BATCH * FD * 4);
    float* hid  = (float*)carve((size_t)BATCH * MH * 4);
    float* cf   = (float*)carve((size_t)BATCH * NT * 4);

    // 1. patchify -> bf16
    {
        int total = M1 * PD;
        patchify_bf<<<(total + 255) / 256, 256, 0, stream>>>(x, p_bf, total);
    }
    // 2. transpose shared weights to [N,K] bf16
    wtrans<<<dim3(PD / 32, PD / 32), 256, 0, stream>>>(W1, W1T, PD, PD);
    wtrans<<<dim3(PD / 32, DH / 32), 256, 0, stream>>>(W2, W2T, PD, DH);
    // 3. phase-1 L1: h = relu(p @ W1 + b1)
    gemm_bf16<<<dim3(PD / GBN, M1 / GBM, 1), 256, 0, stream>>>(
        p_bf, W1T, b1, h_bf, M1, PD, PD, 0, 0, 0, 0, 1);
    // 4. phase-1 L2: h2 = relu(h @ W2 + b2)
    gemm_bf16<<<dim3(DH / GBN, M1 / GBM, 1), 256, 0, stream>>>(
        h_bf, W2T, b2, h2_bf, M1, DH, PD, 0, 0, 0, 0, 1);
    // 5. mean pool -> h2m
    {
        int total = BATCH * DH;
        meanpool_bf<<<(total + 255) / 256, 256, 0, stream>>>(h2_bf, h2m, total, DH);
    }
    // 6. base = h2m @ W3 + b3  (init + split-K skinny GEMM, KS=24)
    compose_bias<<<(BATCH * FD + 255) / 256, 256, 0, stream>>>(b3, nullptr, nullptr, base, FD);
    skinny3<<<dim3(FD / 64, 1, 24), 256, 0, stream>>>(h2m, W3, nullptr, nullptr, base, DH / 24);
    // 7. hid = relu(base @ mW1 + mb1)
    hid_kernel<<<BATCH * MH / 4, 256, 0, stream>>>(base, mW1, mb1, hid);
    // 8. coefs
    coef_kernel<<<1, 256, 0, stream>>>(hid, mW2, mb2, cf);
    // 9. compose per-sample weights (transposed bf16) + biases (fp32)
    compose_w<<<dim3(PD / 32, PD / 32), 256, 0, stream>>>(W1, dW1, cf, W1bT, PD, PD);
    compose_w<<<dim3(PD / 32, DH / 32), 256, 0, stream>>>(W2, dW2, cf, W2bT, PD, DH);
    compose_bias<<<(BATCH * PD + 255) / 256, 256, 0, stream>>>(b1, db1, cf, b1b, PD);
    compose_bias<<<(BATCH * DH + 255) / 256, 256, 0, stream>>>(b2, db2, cf, b2b, DH);
    // 10. phase-2 L1: h = relu(p[b] @ W1b[b] + b1b[b])
    gemm_bf16<<<dim3(PD / GBN, 2, BATCH), 256, 0, stream>>>(
        p_bf, W1bT, b1b, h_bf, NPATCH, PD, PD,
        (long)NPATCH * PD, (long)PD * PD, (long)NPATCH * PD, PD, 1);
    // 11. phase-2 L2: h2 = relu(h[b] @ W2b[b] + b2b[b])
    gemm_bf16<<<dim3(DH / GBN, 2, BATCH), 256, 0, stream>>>(
        h_bf, W2bT, b2b, h2_bf, NPATCH, DH, PD,
        (long)NPATCH * PD, (long)DH * PD, (long)NPATCH * DH, DH, 1);
    // 12. mean pool -> h2m2
    {
        int total = BATCH * DH;
        meanpool_bf<<<(total + 255) / 256, 256, 0, stream>>>(h2_bf, h2m2, total, DH);
    }
    // 13-15. out = (b3 + sum c db3) + h2m2 @ W3 + sum_t c_t (h2m2 @ dW3[t])
    //        one fused skinny GEMM: nz=9, KS=6 (kchunk=512) -> 432 blocks
    compose_bias<<<(BATCH * FD + 255) / 256, 256, 0, stream>>>(b3, db3, cf, out, FD);
    skinny3<<<dim3(FD / 64, 9, 6), 256, 0, stream>>>(h2m2, W3, dW3, cf, out, DH / 6);
}